// Round 5
// baseline (329.311 us; speedup 1.0000x reference)
//
#include <hip/hip_runtime.h>
#include <hip/hip_cooperative_groups.h>

namespace cg = cooperative_groups;

// Problem constants (B=2, H=8, L=1024, D=64)
#define N_HEADS 16          // B*H
#define L_SEQ   1024
#define D_HEAD  64
#define D2      128         // 2*D (sin/cos concat)
#define T_CHUNK 32
#define N_CHUNK (L_SEQ / T_CHUNK)   // 32
#define KV_ELEMS (D2 * D_HEAD)      // 8192

// Padded LDS row: +4 floats every 32 cols; g-group b128 reads land 2-way max.
#define ROWP 140
#define PARTP 132

__device__ __forceinline__ int pad_col(int d2) { return d2 + 4 * (d2 >> 5); }

#define SINCOS_SCALE 1.53398078788564122971e-3f   // (pi/2)/1024

// All-VALU (DPP) reduction over the 8 lanes differing in bits 0..2.
__device__ __forceinline__ float red8_dpp(float x) {
    x += __int_as_float(__builtin_amdgcn_mov_dpp(__float_as_int(x), 0xB1, 0xF, 0xF, true));
    x += __int_as_float(__builtin_amdgcn_mov_dpp(__float_as_int(x), 0x4E, 0xF, 0xF, true));
    x += __int_as_float(__builtin_amdgcn_mov_dpp(__float_as_int(x), 0x141, 0xF, 0xF, true));
    return x;
}

// ---------------------------------------------------------------------------
// Fused kernel: phase A (chunk sums) -> grid sync -> phase B (prefix scan)
// -> grid sync -> phase C (outputs). Block (c,n) keeps its reweighted k/v
// tiles resident in LDS from phase A through phase C.
// ---------------------------------------------------------------------------
__global__ __launch_bounds__(256, 2) void fused_all(
    const float* __restrict__ q, const float* __restrict__ k,
    const float* __restrict__ v, float* __restrict__ sumkv,
    float* __restrict__ sumk, float* __restrict__ out)
{
    __shared__ __attribute__((aligned(16))) float k_s[T_CHUNK][ROWP];
    __shared__ __attribute__((aligned(16))) float q_s[T_CHUNK][ROWP];
    __shared__ __attribute__((aligned(16))) float v_s[T_CHUNK][D_HEAD];
    __shared__ __attribute__((aligned(16))) float pool[T_CHUNK * PARTP]; // part_s / out_s
    __shared__ float rden_s[T_CHUNK];
    __shared__ float s_tab[T_CHUNK], c_tab[T_CHUNK];

    float (*part_s)[PARTP] = (float(*)[PARTP])pool;
    float (*out_s)[D_HEAD] = (float(*)[D_HEAD])pool;

    const int c = blockIdx.x, n = blockIdx.y;
    const int tid = threadIdx.x;
    const int base = (n * L_SEQ + c * T_CHUNK) * D_HEAD;

    cg::grid_group grid = cg::this_grid();

    // ======================= Phase A: chunk-local sums ======================
    if (tid < T_CHUNK) {
        float th = SINCOS_SCALE * (float)(c * T_CHUNK + tid + 1);
        s_tab[tid] = __sinf(th);
        c_tab[tid] = __cosf(th);
    }
    __syncthreads();

    const float4* k4g = (const float4*)(k + base);
    const float4* v4g = (const float4*)(v + base);
#pragma unroll
    for (int j = 0; j < 2; ++j) {
        int i4 = j * 256 + tid;            // 0..511
        int l = i4 >> 4, d = (i4 & 15) << 2;
        float4 kk = k4g[i4], vv = v4g[i4];
        kk.x = fmaxf(kk.x, 0.f); kk.y = fmaxf(kk.y, 0.f);
        kk.z = fmaxf(kk.z, 0.f); kk.w = fmaxf(kk.w, 0.f);
        vv.x = fmaxf(vv.x, 0.f); vv.y = fmaxf(vv.y, 0.f);
        vv.z = fmaxf(vv.z, 0.f); vv.w = fmaxf(vv.w, 0.f);
        float s = s_tab[l], cs = c_tab[l];
        *(float4*)&k_s[l][pad_col(d)]      = make_float4(kk.x*s,  kk.y*s,  kk.z*s,  kk.w*s);
        *(float4*)&k_s[l][pad_col(d + 64)] = make_float4(kk.x*cs, kk.y*cs, kk.z*cs, kk.w*cs);
        *(float4*)&v_s[l][d] = vv;
    }
    __syncthreads();

    // Column sums of k_ -> sumk (local), computed once.
    if (tid < D2) {
        int pc = pad_col(tid);
        float ks = 0.f;
#pragma unroll
        for (int l = 0; l < T_CHUNK; ++l) ks += k_s[l][pc];
        sumk[(n * N_CHUNK + c) * D2 + tid] = ks;
    }

    const int g = tid & 7, mh = (tid >> 3) << 1;
    const int gbase = pad_col(16 * g);

    {
        float st0[16], st1[16];
#pragma unroll
        for (int j = 0; j < 16; ++j) { st0[j] = 0.f; st1[j] = 0.f; }

        for (int l = 0; l < T_CHUNK; ++l) {
            float2 vm = *(const float2*)&v_s[l][mh];
            const float4* kv4 = (const float4*)&k_s[l][gbase];
#pragma unroll
            for (int jj = 0; jj < 4; ++jj) {
                float4 kk = kv4[jj];
                st0[4*jj+0] = fmaf(kk.x, vm.x, st0[4*jj+0]);
                st1[4*jj+0] = fmaf(kk.x, vm.y, st1[4*jj+0]);
                st0[4*jj+1] = fmaf(kk.y, vm.x, st0[4*jj+1]);
                st1[4*jj+1] = fmaf(kk.y, vm.y, st1[4*jj+1]);
                st0[4*jj+2] = fmaf(kk.z, vm.x, st0[4*jj+2]);
                st1[4*jj+2] = fmaf(kk.z, vm.y, st1[4*jj+2]);
                st0[4*jj+3] = fmaf(kk.w, vm.x, st0[4*jj+3]);
                st1[4*jj+3] = fmaf(kk.w, vm.y, st1[4*jj+3]);
            }
        }

        float4* dst = (float4*)(sumkv + (size_t)(n * N_CHUNK + c) * KV_ELEMS);
#pragma unroll
        for (int j4 = 0; j4 < 4; ++j4) {
            dst[(2*j4+0)*256 + tid] = make_float4(st0[4*j4], st0[4*j4+1], st0[4*j4+2], st0[4*j4+3]);
            dst[(2*j4+1)*256 + tid] = make_float4(st1[4*j4], st1[4*j4+1], st1[4*j4+2], st1[4*j4+3]);
        }
    }

    __threadfence();
    grid.sync();

    // ======================= Phase B: exclusive prefix ======================
    // Block (c,n) scans slice c (256 elems) of head n across the 32 chunks.
    {
        float* bse = sumkv + (size_t)n * N_CHUNK * KV_ELEMS + c * 256 + tid;
        float t[N_CHUNK];
#pragma unroll
        for (int cc = 0; cc < N_CHUNK; ++cc) t[cc] = bse[cc * KV_ELEMS];
        float r = 0.f;
#pragma unroll
        for (int cc = 0; cc < N_CHUNK; ++cc) { bse[cc * KV_ELEMS] = r; r += t[cc]; }

        if (c == 0 && tid < D2) {
            float* bk = sumk + n * N_CHUNK * D2 + tid;
            float tk[N_CHUNK];
#pragma unroll
            for (int cc = 0; cc < N_CHUNK; ++cc) tk[cc] = bk[cc * D2];
            float rk = 0.f;
#pragma unroll
            for (int cc = 0; cc < N_CHUNK; ++cc) { bk[cc * D2] = rk; rk += tk[cc]; }
        }
    }

    __threadfence();
    grid.sync();

    // ======================= Phase C: outputs ===============================
    // k_s, v_s, s_tab, c_tab still resident in LDS from phase A.
    const float4* q4g = (const float4*)(q + base);
#pragma unroll
    for (int j = 0; j < 2; ++j) {
        int i4 = j * 256 + tid;
        int l = i4 >> 4, d = (i4 & 15) << 2;
        float4 qq = q4g[i4];
        qq.x = fmaxf(qq.x, 0.f); qq.y = fmaxf(qq.y, 0.f);
        qq.z = fmaxf(qq.z, 0.f); qq.w = fmaxf(qq.w, 0.f);
        float s = s_tab[l], cs = c_tab[l];
        *(float4*)&q_s[l][pad_col(d)]      = make_float4(qq.x*s,  qq.y*s,  qq.z*s,  qq.w*s);
        *(float4*)&q_s[l][pad_col(d + 64)] = make_float4(qq.x*cs, qq.y*cs, qq.z*cs, qq.w*cs);
    }

    // Prefix-state loads (issued early to overlap the LDS phases below).
    const float4* pkv = (const float4*)(sumkv + (size_t)(n * N_CHUNK + c) * KV_ELEMS);
    float st0[16], st1[16];
#pragma unroll
    for (int i = 0; i < 4; ++i) {
        float4 p0 = pkv[(2*i+0) * 256 + tid];
        float4 p1 = pkv[(2*i+1) * 256 + tid];
        st0[4*i+0] = p0.x; st0[4*i+1] = p0.y; st0[4*i+2] = p0.z; st0[4*i+3] = p0.w;
        st1[4*i+0] = p1.x; st1[4*i+1] = p1.y; st1[4*i+2] = p1.z; st1[4*i+3] = p1.w;
    }
    float kc = 0.f;
    if (tid < D2) kc = sumk[(n * N_CHUNK + c) * D2 + tid];

    __syncthreads();

    // Denominator: per-column running k-cumsum * q, once per block.
    if (tid < D2) {
        int pc = pad_col(tid);
#pragma unroll
        for (int l = 0; l < T_CHUNK; ++l) {
            kc += k_s[l][pc];
            part_s[l][tid] = q_s[l][pc] * kc;
        }
    }
    __syncthreads();

    {
        int l = tid >> 3, j = tid & 7;
        const float4* p4 = (const float4*)&part_s[l][j * 16];
        float4 aa = p4[0], bb = p4[1], cc4 = p4[2], dd = p4[3];
        float sum = ((aa.x + aa.y) + (aa.z + aa.w)) + ((bb.x + bb.y) + (bb.z + bb.w))
                  + ((cc4.x + cc4.y) + (cc4.z + cc4.w)) + ((dd.x + dd.y) + (dd.z + dd.w));
        sum = red8_dpp(sum);
        if (j == 0) rden_s[l] = 1.f / fmaxf(sum, 1e-6f);
    }
    __syncthreads();   // part_s dead; pool becomes out_s

    for (int l = 0; l < T_CHUNK; ++l) {
        float2 vm = *(const float2*)&v_s[l][mh];
        const float4* kv4 = (const float4*)&k_s[l][gbase];
        const float4* qv4 = (const float4*)&q_s[l][gbase];
        float a0 = 0.f, a1 = 0.f;
#pragma unroll
        for (int jj = 0; jj < 4; ++jj) {
            float4 kk = kv4[jj];
            float4 qq = qv4[jj];
            st0[4*jj+0] = fmaf(kk.x, vm.x, st0[4*jj+0]); a0 = fmaf(qq.x, st0[4*jj+0], a0);
            st1[4*jj+0] = fmaf(kk.x, vm.y, st1[4*jj+0]); a1 = fmaf(qq.x, st1[4*jj+0], a1);
            st0[4*jj+1] = fmaf(kk.y, vm.x, st0[4*jj+1]); a0 = fmaf(qq.y, st0[4*jj+1], a0);
            st1[4*jj+1] = fmaf(kk.y, vm.y, st1[4*jj+1]); a1 = fmaf(qq.y, st1[4*jj+1], a1);
            st0[4*jj+2] = fmaf(kk.z, vm.x, st0[4*jj+2]); a0 = fmaf(qq.z, st0[4*jj+2], a0);
            st1[4*jj+2] = fmaf(kk.z, vm.y, st1[4*jj+2]); a1 = fmaf(qq.z, st1[4*jj+2], a1);
            st0[4*jj+3] = fmaf(kk.w, vm.x, st0[4*jj+3]); a0 = fmaf(qq.w, st0[4*jj+3], a0);
            st1[4*jj+3] = fmaf(kk.w, vm.y, st1[4*jj+3]); a1 = fmaf(qq.w, st1[4*jj+3], a1);
        }
        a0 = red8_dpp(a0);
        a1 = red8_dpp(a1);
        if (g == 0) {
            float r = rden_s[l];
            *(float2*)&out_s[l][mh] = make_float2(a0 * r, a1 * r);
        }
    }
    __syncthreads();

    // Coalesced output store.
    {
        float4* o4 = (float4*)(out + base);
        const float4* s4o = (const float4*)&out_s[0][0];
        o4[tid] = s4o[tid];
        o4[256 + tid] = s4o[256 + tid];
    }
}

// ---------------------------------------------------------------------------
extern "C" void kernel_launch(void* const* d_in, const int* in_sizes, int n_in,
                              void* d_out, int out_size, void* d_ws, size_t ws_size,
                              hipStream_t stream) {
    (void)in_sizes; (void)n_in; (void)out_size; (void)ws_size;
    const float* q = (const float*)d_in[0];
    const float* k = (const float*)d_in[1];
    const float* v = (const float*)d_in[2];
    float* out = (float*)d_out;

    float* sumkv = (float*)d_ws;                                   // [N][C][8192] flat
    float* sumk  = sumkv + (size_t)N_HEADS * N_CHUNK * KV_ELEMS;   // [N][C][128]

    void* args[] = {(void*)&q, (void*)&k, (void*)&v,
                    (void*)&sumkv, (void*)&sumk, (void*)&out};
    hipLaunchCooperativeKernel((const void*)fused_all,
                               dim3(N_CHUNK, N_HEADS), dim3(256),
                               args, 0, stream);
}

// Round 6
// 93.846 us; speedup vs baseline: 3.5091x; 3.5091x over previous
//
#include <hip/hip_runtime.h>

// Problem constants (B=2, H=8, L=1024, D=64)
#define N_HEADS 16          // B*H
#define L_SEQ   1024
#define D_HEAD  64
#define D2      128         // 2*D (sin/cos concat)
#define T_CHUNK 32
#define N_CHUNK (L_SEQ / T_CHUNK)   // 32
#define KV_ELEMS (D2 * D_HEAD)      // 8192

// Padded LDS row: +4 floats every 32 cols; the 16 g-groups' b128 reads then
// hit each bank at most 2-way (free, m136).
#define ROWP 140
#define PARTP 132

__device__ __forceinline__ int pad_col(int d2) { return d2 + 4 * (d2 >> 5); }

#define SINCOS_SCALE 1.53398078788564122971e-3f   // (pi/2)/1024

// All-VALU (DPP) lane reductions; LDS pipe stays free.
// 0xB1 = quad_perm lane^1 ; 0x4E = quad_perm lane^2 ;
// 0x141 = row_half_mirror (^4 once quads uniform) ;
// 0x140 = row_mirror (^8 once 8-groups uniform).
__device__ __forceinline__ float red16_dpp(float x) {
    x += __int_as_float(__builtin_amdgcn_mov_dpp(__float_as_int(x), 0xB1, 0xF, 0xF, true));
    x += __int_as_float(__builtin_amdgcn_mov_dpp(__float_as_int(x), 0x4E, 0xF, 0xF, true));
    x += __int_as_float(__builtin_amdgcn_mov_dpp(__float_as_int(x), 0x141, 0xF, 0xF, true));
    x += __int_as_float(__builtin_amdgcn_mov_dpp(__float_as_int(x), 0x140, 0xF, 0xF, true));
    return x;
}

// ---------------------------------------------------------------------------
// K1: per-(chunk, head) local sums. 512 threads; thread owns 8 d2-cols
// (g = tid&15) x 2 m-cols. 16 waves/CU for latency hiding.
// ---------------------------------------------------------------------------
__global__ __launch_bounds__(512, 4) void k1_chunk_sums(
    const float* __restrict__ k, const float* __restrict__ v,
    float* __restrict__ sumkv, float* __restrict__ sumk)
{
    __shared__ __attribute__((aligned(16))) float k_s[T_CHUNK][ROWP];
    __shared__ __attribute__((aligned(16))) float v_s[T_CHUNK][D_HEAD];
    __shared__ float s_tab[T_CHUNK], c_tab[T_CHUNK];

    const int c = blockIdx.x, n = blockIdx.y;
    const int tid = threadIdx.x;
    const int base = (n * L_SEQ + c * T_CHUNK) * D_HEAD;

    if (tid < T_CHUNK) {
        float th = SINCOS_SCALE * (float)(c * T_CHUNK + tid + 1);
        s_tab[tid] = __sinf(th);
        c_tab[tid] = __cosf(th);
    }
    __syncthreads();

    // Stage: one float4 per thread per stream.
    {
        const float4* k4g = (const float4*)(k + base);
        const float4* v4g = (const float4*)(v + base);
        int l = tid >> 4, d = (tid & 15) << 2;
        float4 kk = k4g[tid], vv = v4g[tid];
        kk.x = fmaxf(kk.x, 0.f); kk.y = fmaxf(kk.y, 0.f);
        kk.z = fmaxf(kk.z, 0.f); kk.w = fmaxf(kk.w, 0.f);
        vv.x = fmaxf(vv.x, 0.f); vv.y = fmaxf(vv.y, 0.f);
        vv.z = fmaxf(vv.z, 0.f); vv.w = fmaxf(vv.w, 0.f);
        float s = s_tab[l], cs = c_tab[l];
        *(float4*)&k_s[l][pad_col(d)]      = make_float4(kk.x*s,  kk.y*s,  kk.z*s,  kk.w*s);
        *(float4*)&k_s[l][pad_col(d + 64)] = make_float4(kk.x*cs, kk.y*cs, kk.z*cs, kk.w*cs);
        *(float4*)&v_s[l][d] = vv;
    }
    __syncthreads();

    // Column sums of k_ -> sumk, computed once.
    if (tid < D2) {
        int pc = pad_col(tid);
        float ks = 0.f;
#pragma unroll
        for (int l = 0; l < T_CHUNK; ++l) ks += k_s[l][pc];
        sumk[(n * N_CHUNK + c) * D2 + tid] = ks;
    }

    const int g = tid & 15, mh = (tid >> 4) << 1;
    const int gbase = pad_col(8 * g);

    float st0[8], st1[8];
#pragma unroll
    for (int j = 0; j < 8; ++j) { st0[j] = 0.f; st1[j] = 0.f; }

    for (int l = 0; l < T_CHUNK; ++l) {
        float2 vm = *(const float2*)&v_s[l][mh];
        const float4* kf4 = (const float4*)&k_s[l][gbase];
        float4 ka = kf4[0], kb = kf4[1];
        float kf[8] = {ka.x, ka.y, ka.z, ka.w, kb.x, kb.y, kb.z, kb.w};
#pragma unroll
        for (int i = 0; i < 8; ++i) {
            st0[i] = fmaf(kf[i], vm.x, st0[i]);
            st1[i] = fmaf(kf[i], vm.y, st1[i]);
        }
    }

    // Coalesced float4 stores, thread-interleaved flat layout (K3 mirrors it).
    float4* dst = (float4*)(sumkv + (size_t)(n * N_CHUNK + c) * KV_ELEMS);
    dst[0 * 512 + tid] = make_float4(st0[0], st0[1], st0[2], st0[3]);
    dst[1 * 512 + tid] = make_float4(st0[4], st0[5], st0[6], st0[7]);
    dst[2 * 512 + tid] = make_float4(st1[0], st1[1], st1[2], st1[3]);
    dst[3 * 512 + tid] = make_float4(st1[4], st1[5], st1[6], st1[7]);
}

// ---------------------------------------------------------------------------
// K2: exclusive prefix over chunks, float4/thread, two 16-deep dwordx4
// load pipelines (data-independent addresses -> MLP), 1 KB/wave-instruction.
// ---------------------------------------------------------------------------
__global__ __launch_bounds__(256) void k2_prefix(
    float* __restrict__ sumkv, float* __restrict__ sumk)
{
    const int x = blockIdx.x, n = blockIdx.y;
    const int tid = threadIdx.x;

    if (x < 8) {
        float4* base = (float4*)(sumkv + (size_t)n * N_CHUNK * KV_ELEMS) + x * 256 + tid;
        float4 r = make_float4(0.f, 0.f, 0.f, 0.f);
        float4 t[16];
#pragma unroll
        for (int h = 0; h < 2; ++h) {
#pragma unroll
            for (int c = 0; c < 16; ++c) t[c] = base[(h * 16 + c) * (KV_ELEMS / 4)];
#pragma unroll
            for (int c = 0; c < 16; ++c) {
                base[(h * 16 + c) * (KV_ELEMS / 4)] = r;
                r.x += t[c].x; r.y += t[c].y; r.z += t[c].z; r.w += t[c].w;
            }
        }
    } else if (tid < D2) {
        float* bk = sumk + n * N_CHUNK * D2 + tid;
        float t[N_CHUNK];
#pragma unroll
        for (int c = 0; c < N_CHUNK; ++c) t[c] = bk[c * D2];
        float r = 0.f;
#pragma unroll
        for (int c = 0; c < N_CHUNK; ++c) { bk[c * D2] = r; r += t[c]; }
    }
}

// ---------------------------------------------------------------------------
// K3: outputs. 512 threads, (8 d2-cols x 2 m-cols)/thread, DPP red16,
// denominator precomputed once per block; part_s overlaid with out_s.
// ---------------------------------------------------------------------------
__global__ __launch_bounds__(512, 4) void k3_output(
    const float* __restrict__ q, const float* __restrict__ k,
    const float* __restrict__ v, const float* __restrict__ sumkv,
    const float* __restrict__ sumk, float* __restrict__ out)
{
    __shared__ __attribute__((aligned(16))) float k_s[T_CHUNK][ROWP];
    __shared__ __attribute__((aligned(16))) float q_s[T_CHUNK][ROWP];
    __shared__ __attribute__((aligned(16))) float v_s[T_CHUNK][D_HEAD];
    __shared__ __attribute__((aligned(16))) float pool[T_CHUNK * PARTP]; // part_s / out_s
    __shared__ float rden_s[T_CHUNK];
    __shared__ float s_tab[T_CHUNK], c_tab[T_CHUNK];

    float (*part_s)[PARTP] = (float(*)[PARTP])pool;
    float (*out_s)[D_HEAD] = (float(*)[D_HEAD])pool;

    const int c = blockIdx.x, n = blockIdx.y;
    const int tid = threadIdx.x;
    const int base = (n * L_SEQ + c * T_CHUNK) * D_HEAD;

    if (tid < T_CHUNK) {
        float th = SINCOS_SCALE * (float)(c * T_CHUNK + tid + 1);
        s_tab[tid] = __sinf(th);
        c_tab[tid] = __cosf(th);
    }
    __syncthreads();

    {
        const float4* q4g = (const float4*)(q + base);
        const float4* k4g = (const float4*)(k + base);
        const float4* v4g = (const float4*)(v + base);
        int l = tid >> 4, d = (tid & 15) << 2;
        float4 kk = k4g[tid], qq = q4g[tid], vv = v4g[tid];
        kk.x = fmaxf(kk.x, 0.f); kk.y = fmaxf(kk.y, 0.f);
        kk.z = fmaxf(kk.z, 0.f); kk.w = fmaxf(kk.w, 0.f);
        qq.x = fmaxf(qq.x, 0.f); qq.y = fmaxf(qq.y, 0.f);
        qq.z = fmaxf(qq.z, 0.f); qq.w = fmaxf(qq.w, 0.f);
        vv.x = fmaxf(vv.x, 0.f); vv.y = fmaxf(vv.y, 0.f);
        vv.z = fmaxf(vv.z, 0.f); vv.w = fmaxf(vv.w, 0.f);
        float s = s_tab[l], cs = c_tab[l];
        *(float4*)&k_s[l][pad_col(d)]      = make_float4(kk.x*s,  kk.y*s,  kk.z*s,  kk.w*s);
        *(float4*)&k_s[l][pad_col(d + 64)] = make_float4(kk.x*cs, kk.y*cs, kk.z*cs, kk.w*cs);
        *(float4*)&q_s[l][pad_col(d)]      = make_float4(qq.x*s,  qq.y*s,  qq.z*s,  qq.w*s);
        *(float4*)&q_s[l][pad_col(d + 64)] = make_float4(qq.x*cs, qq.y*cs, qq.z*cs, qq.w*cs);
        *(float4*)&v_s[l][d] = vv;
    }

    // Prefix state loads issued before the barrier (latency overlap).
    const float4* pkv = (const float4*)(sumkv + (size_t)(n * N_CHUNK + c) * KV_ELEMS);
    float st0[8], st1[8];
    {
        float4 p0 = pkv[0 * 512 + tid];
        float4 p1 = pkv[1 * 512 + tid];
        float4 p2 = pkv[2 * 512 + tid];
        float4 p3 = pkv[3 * 512 + tid];
        st0[0]=p0.x; st0[1]=p0.y; st0[2]=p0.z; st0[3]=p0.w;
        st0[4]=p1.x; st0[5]=p1.y; st0[6]=p1.z; st0[7]=p1.w;
        st1[0]=p2.x; st1[1]=p2.y; st1[2]=p2.z; st1[3]=p2.w;
        st1[4]=p3.x; st1[5]=p3.y; st1[6]=p3.z; st1[7]=p3.w;
    }
    float kc = 0.f;
    if (tid < D2) kc = sumk[(n * N_CHUNK + c) * D2 + tid];

    __syncthreads();

    // Denominator: per-column running k-cumsum * q, once per block.
    if (tid < D2) {
        int pc = pad_col(tid);
#pragma unroll
        for (int l = 0; l < T_CHUNK; ++l) {
            kc += k_s[l][pc];
            part_s[l][tid] = q_s[l][pc] * kc;
        }
    }
    __syncthreads();

    // Row-reduce part_s -> 1/den. 16 lanes per row, DPP red16.
    {
        int l = tid >> 4, j = tid & 15;
        const float4* p4 = (const float4*)&part_s[l][j * 8];
        float4 aa = p4[0], bb = p4[1];
        float sum = ((aa.x + aa.y) + (aa.z + aa.w)) + ((bb.x + bb.y) + (bb.z + bb.w));
        sum = red16_dpp(sum);
        if (j == 0) rden_s[l] = 1.f / fmaxf(sum, 1e-6f);
    }
    __syncthreads();   // part_s dead; pool becomes out_s

    const int g = tid & 15, mh = (tid >> 4) << 1;
    const int gbase = pad_col(8 * g);

    for (int l = 0; l < T_CHUNK; ++l) {
        float2 vm = *(const float2*)&v_s[l][mh];
        const float4* kf4 = (const float4*)&k_s[l][gbase];
        const float4* qf4 = (const float4*)&q_s[l][gbase];
        float4 ka = kf4[0], kb = kf4[1];
        float4 qa = qf4[0], qb = qf4[1];
        float kf[8] = {ka.x, ka.y, ka.z, ka.w, kb.x, kb.y, kb.z, kb.w};
        float qf[8] = {qa.x, qa.y, qa.z, qa.w, qb.x, qb.y, qb.z, qb.w};
        float a0 = 0.f, a1 = 0.f;
#pragma unroll
        for (int i = 0; i < 8; ++i) {
            st0[i] = fmaf(kf[i], vm.x, st0[i]); a0 = fmaf(qf[i], st0[i], a0);
            st1[i] = fmaf(kf[i], vm.y, st1[i]); a1 = fmaf(qf[i], st1[i], a1);
        }
        a0 = red16_dpp(a0);
        a1 = red16_dpp(a1);
        if (g == 0) {
            float r = rden_s[l];
            *(float2*)&out_s[l][mh] = make_float2(a0 * r, a1 * r);
        }
    }
    __syncthreads();

    // Coalesced output store.
    {
        float4* o4 = (float4*)(out + base);
        const float4* s4o = (const float4*)&out_s[0][0];
        o4[tid] = s4o[tid];
    }
}

// ---------------------------------------------------------------------------
extern "C" void kernel_launch(void* const* d_in, const int* in_sizes, int n_in,
                              void* d_out, int out_size, void* d_ws, size_t ws_size,
                              hipStream_t stream) {
    (void)in_sizes; (void)n_in; (void)out_size; (void)ws_size;
    const float* q = (const float*)d_in[0];
    const float* k = (const float*)d_in[1];
    const float* v = (const float*)d_in[2];
    float* out = (float*)d_out;

    float* sumkv = (float*)d_ws;                                   // [N][C][8192] flat
    float* sumk  = sumkv + (size_t)N_HEADS * N_CHUNK * KV_ELEMS;   // [N][C][128]

    dim3 grid(N_CHUNK, N_HEADS);
    k1_chunk_sums<<<grid, 512, 0, stream>>>(k, v, sumkv, sumk);
    dim3 grid2(9, N_HEADS);
    k2_prefix<<<grid2, 256, 0, stream>>>(sumkv, sumk);
    k3_output<<<grid, 512, 0, stream>>>(q, k, v, sumkv, sumk, out);
}